// Round 9
// baseline (155.565 us; speedup 1.0000x reference)
//
#include <hip/hip_runtime.h>

// ContrastiveQueueLoss: V (2,256,128) f32, L (256,128) f32, queue (65536,128) f32
// loss = -(1/256) * sum_{m<512} ( pos[m] - log( Spos[j(m)] + Sq[m] ) )

typedef float  float4v __attribute__((ext_vector_type(4)));
typedef short  short8  __attribute__((ext_vector_type(8)));

__device__ __forceinline__ unsigned short f2bf(float f) {
    union { float f; unsigned u; } v; v.f = f;
    unsigned r = v.u + 0x7FFFu + ((v.u >> 16) & 1u);   // RNE (inputs finite)
    return (unsigned short)(r >> 16);
}
__device__ __forceinline__ unsigned pk2(float x, float y) {
    return (unsigned)f2bf(x) | ((unsigned)f2bf(y) << 16);
}

// ======================================================= fast path =========

// 64 blocks x 256: V -> bf16 (abf); block 0 tid 0 zeroes the ticket.
__global__ __launch_bounds__(256) void prep_kernel_fast(
        const float* __restrict__ V, unsigned short* __restrict__ abf,
        unsigned int* __restrict__ ticket) {
    const int tid = threadIdx.x;
    const int gt  = blockIdx.x * 256 + tid;           // 16384 float4s
    const float4 v = ((const float4*)V)[gt];
    uint2 p;
    p.x = pk2(v.x, v.y);
    p.y = pk2(v.z, v.w);
    ((uint2*)abf)[gt] = p;
    if (blockIdx.x == 0 && tid == 0) *ticket = 0u;
}

// 512 blocks x 256 threads (2 blocks/CU, 32 KB LDS). Block bid owns queue
// rows [bid*128, bid*128+128): reads once as fp32 (64 KB contiguous),
// converts RNE to bf16 into one XOR-swizzled LDS tile, computes both 256-row
// M tiles (2 subtiles of 64 q-rows each), exp-folds into register row sums,
// ONE barrier total, direct float4 stores to gbuf[bid*512 + m].
// LDS layout: element (row, k) at row*128 + (((k>>3) ^ (row&15))<<3) + (k&7).
__global__ __launch_bounds__(256, 2) void gemm_exp_512_kernel(
        const unsigned short* __restrict__ abf,
        const float* __restrict__ Qf,
        float* __restrict__ gbuf) {
    __shared__ unsigned short Bs[128 * 128];      // 32 KB

    const int tid  = threadIdx.x;
    const int bid  = blockIdx.x;
    const int nb   = bid * 128;                   // queue row base

    const int w    = tid >> 6;
    const int lane = tid & 63;
    const int quad = lane >> 4;
    const int l16  = lane & 15;
    const int wrow = w * 64;                      // wave owns 64 M rows / mt

    // ---- stage B: 128x128 fp32 -> bf16, swizzled (16 float4/thread) ----
    #pragma unroll
    for (int i = 0; i < 16; ++i) {
        const int idx = i * 256 + tid;            // float4 index in tile
        const int row = idx >> 5;
        const int c4  = idx & 31;
        const float4 q = *reinterpret_cast<const float4*>(Qf + (nb + row) * 128 + c4 * 4);
        uint2 p;
        p.x = pk2(q.x, q.y);
        p.y = pk2(q.z, q.w);
        const int chunk = (c4 >> 1) ^ (row & 15);
        *reinterpret_cast<uint2*>(&Bs[row * 128 + (chunk << 3) + ((c4 & 1) << 2)]) = p;
    }

    // Prefetch mt=0 A-frags while Bs staging drains (independent of LDS).
    short8 a[4][4];
    #pragma unroll
    for (int mi = 0; mi < 4; ++mi)
        #pragma unroll
        for (int kk = 0; kk < 4; ++kk)
            a[mi][kk] = *(const short8*)&abf[(wrow + mi * 16 + l16) * 128
                                             + (kk * 4 + quad) * 8];
    __syncthreads();                               // the ONLY barrier

    #pragma unroll 1
    for (int mt = 0; mt < 2; ++mt) {
        float rs[4][4];
        #pragma unroll
        for (int mi = 0; mi < 4; ++mi)
            #pragma unroll
            for (int r = 0; r < 4; ++r) rs[mi][r] = 0.0f;

        #pragma unroll
        for (int sub = 0; sub < 2; ++sub) {       // 64 queue rows each
            float4v acc[4][4];
            #pragma unroll
            for (int mi = 0; mi < 4; ++mi)
                #pragma unroll
                for (int ni = 0; ni < 4; ++ni)
                    acc[mi][ni] = (float4v){0.f, 0.f, 0.f, 0.f};

            #pragma unroll
            for (int kk = 0; kk < 4; ++kk) {
                const int c = kk * 4 + quad;
                short8 b[4];
                #pragma unroll
                for (int ni = 0; ni < 4; ++ni) {
                    const int row = sub * 64 + ni * 16 + l16;
                    b[ni] = *(const short8*)&Bs[row * 128 + ((c ^ (row & 15)) << 3)];
                }
                #pragma unroll
                for (int mi = 0; mi < 4; ++mi)
                    #pragma unroll
                    for (int ni = 0; ni < 4; ++ni)
                        acc[mi][ni] = __builtin_amdgcn_mfma_f32_16x16x32_bf16(
                            a[mi][kk], b[ni], acc[mi][ni], 0, 0, 0);
            }

            // exp(10*x) = 2^(x * 10/ln2)
            #pragma unroll
            for (int mi = 0; mi < 4; ++mi)
                #pragma unroll
                for (int ni = 0; ni < 4; ++ni)
                    #pragma unroll
                    for (int r = 0; r < 4; ++r)
                        rs[mi][r] += exp2f(acc[mi][ni][r] * 14.426950408889634f);
        }

        if (mt == 0) {                             // prefetch mt=1 A under exp
            #pragma unroll
            for (int mi = 0; mi < 4; ++mi)
                #pragma unroll
                for (int kk = 0; kk < 4; ++kk)
                    a[mi][kk] = *(const short8*)&abf[(256 + wrow + mi * 16 + l16) * 128
                                                     + (kk * 4 + quad) * 8];
        }

        // reduce over 16 n-cols; lane l16==0 holds contiguous rows quad*4..+3
        #pragma unroll
        for (int mi = 0; mi < 4; ++mi) {
            #pragma unroll
            for (int r = 0; r < 4; ++r) {
                rs[mi][r] += __shfl_xor(rs[mi][r], 1);
                rs[mi][r] += __shfl_xor(rs[mi][r], 2);
                rs[mi][r] += __shfl_xor(rs[mi][r], 4);
                rs[mi][r] += __shfl_xor(rs[mi][r], 8);
            }
            if (l16 == 0)
                *reinterpret_cast<float4*>(
                    &gbuf[bid * 512 + mt * 256 + wrow + mi * 16 + quad * 4]) =
                    make_float4(rs[mi][0], rs[mi][1], rs[mi][2], rs[mi][3]);
        }
    }
}

// Backend: 32 blocks x 1024. Phase A: block b reduces gbuf slices
// [b*16, b*16+16) -> gbuf2[b*512+m] (coalesced). Then fence + ticket; the
// LAST block re-reads all 32 slices via agent-scope atomic loads, computes
// pos from L2-hot V.L, Sp, and the loss.
__global__ __launch_bounds__(1024) void backend_kernel(
        const float* __restrict__ V, const float* __restrict__ L,
        const float* __restrict__ gbuf, float* __restrict__ gbuf2,
        unsigned int* __restrict__ ticket, float* __restrict__ out) {
    __shared__ float comb[1024];
    __shared__ float comb2[1024];
    __shared__ float wsum[16];
    __shared__ unsigned int lastFlag;

    const int tid  = threadIdx.x;
    const int b    = blockIdx.x;
    const int m    = tid & 511;
    const int h    = tid >> 9;                     // 0/1
    const int w    = tid >> 6;
    const int lane = tid & 63;

    // ---- phase A: fold 16 slices -> 1 ----
    {
        float s = 0.0f;
        const int sbase = b * 16 + h * 8;
        #pragma unroll
        for (int k = 0; k < 8; ++k)
            s += gbuf[((sbase + k) << 9) + m];
        comb[tid] = s;
    }
    __syncthreads();
    if (tid < 512) gbuf2[(b << 9) + tid] = comb[tid] + comb[tid + 512];
    __threadfence();
    __syncthreads();
    if (tid == 0) lastFlag = (atomicAdd(ticket, 1u) == 31u) ? 1u : 0u;
    __syncthreads();
    if (lastFlag == 0u) return;
    __threadfence();

    // ---- last block: Sq[m] from gbuf2 (agent-scope loads) ----
    {
        float s = 0.0f;
        #pragma unroll
        for (int k = 0; k < 16; ++k)
            s += __hip_atomic_load(&gbuf2[((h * 16 + k) << 9) + m],
                                   __ATOMIC_RELAXED, __HIP_MEMORY_SCOPE_AGENT);
        comb[tid] = s;
    }
    // pos[m] = 10 * dot(V[m], L[m&255]) — split over h halves
    {
        const float4* vr = (const float4*)(V + m * 128 + h * 64);
        const float4* lr = (const float4*)(L + (m & 255) * 128 + h * 64);
        float d = 0.0f;
        #pragma unroll
        for (int i = 0; i < 16; ++i) {
            const float4 a4 = vr[i];
            const float4 b4 = lr[i];
            d += a4.x * b4.x + a4.y * b4.y + a4.z * b4.z + a4.w * b4.w;
        }
        comb2[tid] = 10.0f * d;
    }
    __syncthreads();

    float Sqm = 0.0f, posm = 0.0f;
    if (tid < 512) {
        Sqm  = comb[tid] + comb[tid + 512];
        posm = comb2[tid] + comb2[tid + 512];
    }

    // Sp[j] = sum_b exp(pos[j*256+b]); t<512 spans waves 0..7 (j = t>>8)
    float e = (tid < 512) ? __expf(posm) : 0.0f;
    #pragma unroll
    for (int off = 32; off; off >>= 1) e += __shfl_xor(e, off);
    if (lane == 0) wsum[w] = e;
    __syncthreads();
    const float Sp0 = wsum[0] + wsum[1] + wsum[2] + wsum[3];
    const float Sp1 = wsum[4] + wsum[5] + wsum[6] + wsum[7];

    float contrib = 0.0f;
    if (tid < 512) contrib = posm - __logf(((tid >> 8) ? Sp1 : Sp0) + Sqm);
    #pragma unroll
    for (int off = 32; off; off >>= 1) contrib += __shfl_xor(contrib, off);
    __syncthreads();
    if (lane == 0) wsum[w] = contrib;
    __syncthreads();
    if (tid == 0) {
        float tot = 0.0f;
        #pragma unroll
        for (int i = 0; i < 8; ++i) tot += wsum[i];
        out[0] = -tot / 256.0f;
    }
}

// ======================================================= fallback path ====

__global__ void prep_kernel(const float* __restrict__ V,
                            const float* __restrict__ L,
                            float* __restrict__ pos,
                            float* __restrict__ Sq) {
    const int blk  = blockIdx.x;
    const int tid  = threadIdx.x;
    if (tid < 8) Sq[blk * 8 + tid] = 0.0f;
    const int w    = tid >> 6;
    const int lane = tid & 63;
    #pragma unroll
    for (int i = 0; i < 2; ++i) {
        const int r = blk * 8 + w * 2 + i;
        const int b = r & 255;
        const float2 v = *reinterpret_cast<const float2*>(V + r * 128 + lane * 2);
        const float2 l = *reinterpret_cast<const float2*>(L + b * 128 + lane * 2);
        float p = v.x * l.x + v.y * l.y;
        #pragma unroll
        for (int off = 32; off; off >>= 1) p += __shfl_xor(p, off);
        if (lane == 0) pos[r] = 10.0f * p;
    }
}

__global__ __launch_bounds__(256) void gemm_exp_fallback(
        const float* __restrict__ V,
        const float* __restrict__ Q,
        float* __restrict__ Sq) {
    __shared__ unsigned short As[128 * 128];
    __shared__ unsigned short Bs[128 * 128];
    const int tid = threadIdx.x;
    const int m0  = blockIdx.y * 128;
    const int n0  = blockIdx.x * 128;
    #pragma unroll
    for (int i = 0; i < 16; ++i) {
        const int idx = i * 256 + tid;
        const int row = idx >> 5;
        const int c4  = idx & 31;
        const float4 a = *reinterpret_cast<const float4*>(V + (m0 + row) * 128 + c4 * 4);
        const float4 b = *reinterpret_cast<const float4*>(Q + (n0 + row) * 128 + c4 * 4);
        const int chunk = ((c4 >> 1) ^ (row & 15));
        const int off   = row * 128 + (chunk << 3) + ((c4 & 1) << 2);
        const uint2 pa = make_uint2(pk2(a.x, a.y), pk2(a.z, a.w));
        const uint2 pb = make_uint2(pk2(b.x, b.y), pk2(b.z, b.w));
        *reinterpret_cast<uint2*>(&As[off]) = pa;
        *reinterpret_cast<uint2*>(&Bs[off]) = pb;
    }
    __syncthreads();
    const int w    = tid >> 6;
    const int lane = tid & 63;
    const int quad = lane >> 4;
    const int l16  = lane & 15;
    const int wrow = (w >> 1) * 64;
    const int wcol = (w & 1) * 64;
    float4v acc[4][4];
    #pragma unroll
    for (int mi = 0; mi < 4; ++mi)
        #pragma unroll
        for (int ni = 0; ni < 4; ++ni)
            acc[mi][ni] = (float4v){0.f, 0.f, 0.f, 0.f};
    #pragma unroll
    for (int kk = 0; kk < 4; ++kk) {
        const int kchunk = kk * 4 + quad;
        short8 a[4], b[4];
        #pragma unroll
        for (int mi = 0; mi < 4; ++mi) {
            const int row = wrow + mi * 16 + l16;
            a[mi] = *reinterpret_cast<const short8*>(&As[row * 128 + ((kchunk ^ (row & 15)) << 3)]);
        }
        #pragma unroll
        for (int ni = 0; ni < 4; ++ni) {
            const int row = wcol + ni * 16 + l16;
            b[ni] = *reinterpret_cast<const short8*>(&Bs[row * 128 + ((kchunk ^ (row & 15)) << 3)]);
        }
        #pragma unroll
        for (int mi = 0; mi < 4; ++mi)
            #pragma unroll
            for (int ni = 0; ni < 4; ++ni)
                acc[mi][ni] = __builtin_amdgcn_mfma_f32_16x16x32_bf16(a[mi], b[ni], acc[mi][ni], 0, 0, 0);
    }
    __syncthreads();
    float* rowsum = reinterpret_cast<float*>(As);
    #pragma unroll
    for (int mi = 0; mi < 4; ++mi) {
        float rsv[4] = {0.f, 0.f, 0.f, 0.f};
        #pragma unroll
        for (int ni = 0; ni < 4; ++ni)
            #pragma unroll
            for (int r = 0; r < 4; ++r)
                rsv[r] += __expf(10.0f * acc[mi][ni][r]);
        #pragma unroll
        for (int r = 0; r < 4; ++r) {
            float vsum = rsv[r];
            vsum += __shfl_xor(vsum, 1);
            vsum += __shfl_xor(vsum, 2);
            vsum += __shfl_xor(vsum, 4);
            vsum += __shfl_xor(vsum, 8);
            if (l16 == 0)
                rowsum[(w & 1) * 128 + wrow + mi * 16 + quad * 4 + r] = vsum;
        }
    }
    __syncthreads();
    if (tid < 128)
        atomicAdd(&Sq[m0 + tid], rowsum[tid] + rowsum[128 + tid]);
}

__global__ void finalize_kernel(const float* __restrict__ pos,
                                const float* __restrict__ Sq,
                                float* __restrict__ out) {
    __shared__ float wsum[8];
    __shared__ float Sp[2];
    const int tid  = threadIdx.x;
    const int w    = tid >> 6;
    const int lane = tid & 63;
    const float p = pos[tid];
    float e = __expf(p);
    #pragma unroll
    for (int off = 32; off; off >>= 1) e += __shfl_xor(e, off);
    if (lane == 0) wsum[w] = e;
    __syncthreads();
    if (tid == 0) {
        Sp[0] = wsum[0] + wsum[1] + wsum[2] + wsum[3];
        Sp[1] = wsum[4] + wsum[5] + wsum[6] + wsum[7];
    }
    __syncthreads();
    const int j = tid >> 8;
    float contrib = p - __logf(Sp[j] + Sq[tid]);
    #pragma unroll
    for (int off = 32; off; off >>= 1) contrib += __shfl_xor(contrib, off);
    if (lane == 0) wsum[w] = contrib;
    __syncthreads();
    if (tid == 0) {
        float tot = 0.f;
        #pragma unroll
        for (int i = 0; i < 8; ++i) tot += wsum[i];
        out[0] = -tot / 256.0f;
    }
}

// ======================================================= launch ===========

extern "C" void kernel_launch(void* const* d_in, const int* in_sizes, int n_in,
                              void* d_out, int out_size, void* d_ws, size_t ws_size,
                              hipStream_t stream) {
    const float* V     = (const float*)d_in[0];   // (2,256,128)
    const float* L     = (const float*)d_in[1];   // (256,128)
    const float* queue = (const float*)d_in[2];   // (65536,128)
    float* out = (float*)d_out;

    const size_t need = (size_t)512 * 128 * 2 + (size_t)512 * 512 * 4
                      + (size_t)32 * 512 * 4 + 64;
    if (ws_size >= need) {
        unsigned short* abf = (unsigned short*)d_ws;          // 512x128 bf16
        float* gbuf  = (float*)(abf + 512 * 128);             // 512x512
        float* gbuf2 = gbuf + (size_t)512 * 512;              // 32x512
        unsigned int* tick = (unsigned int*)(gbuf2 + 32 * 512);
        prep_kernel_fast<<<64, 256, 0, stream>>>(V, abf, tick);
        gemm_exp_512_kernel<<<512, 256, 0, stream>>>(abf, queue, gbuf);
        backend_kernel<<<32, 1024, 0, stream>>>(V, L, gbuf, gbuf2, tick, out);
    } else {
        float* pos = (float*)d_ws;
        float* Sq  = pos + 512;
        prep_kernel<<<64, 256, 0, stream>>>(V, L, pos, Sq);
        dim3 grid(512, 4);
        gemm_exp_fallback<<<grid, 256, 0, stream>>>(V, queue, Sq);
        finalize_kernel<<<1, 512, 0, stream>>>(pos, Sq, out);
    }
}

// Round 10
// 131.207 us; speedup vs baseline: 1.1856x; 1.1856x over previous
//
#include <hip/hip_runtime.h>

// ContrastiveQueueLoss: V (2,256,128) f32, L (256,128) f32, queue (65536,128) f32
// loss = -(1/256) * sum_{m<512} ( pos[m] - log( Spos[j(m)] + Sq[m] ) )

typedef float  float4v __attribute__((ext_vector_type(4)));
typedef short  short8  __attribute__((ext_vector_type(8)));

__device__ __forceinline__ unsigned short f2bf(float f) {
    union { float f; unsigned u; } v; v.f = f;
    unsigned r = v.u + 0x7FFFu + ((v.u >> 16) & 1u);   // RNE (inputs finite)
    return (unsigned short)(r >> 16);
}
__device__ __forceinline__ unsigned pk2(float x, float y) {
    return (unsigned)f2bf(x) | ((unsigned)f2bf(y) << 16);
}

// ======================================================= fast path =========

// 64 blocks x 256: V -> bf16 (abf); block 0 tid 0 zeroes the ticket.
__global__ __launch_bounds__(256) void prep_kernel_fast(
        const float* __restrict__ V, unsigned short* __restrict__ abf,
        unsigned int* __restrict__ ticket) {
    const int tid = threadIdx.x;
    const int gt  = blockIdx.x * 256 + tid;           // 16384 float4s
    const float4 v = ((const float4*)V)[gt];
    uint2 p;
    p.x = pk2(v.x, v.y);
    p.y = pk2(v.z, v.w);
    ((uint2*)abf)[gt] = p;
    if (blockIdx.x == 0 && tid == 0) *ticket = 0u;
}

// 512 blocks x 256 threads. Block bid owns queue rows [bid*128, bid*128+128):
// reads once as fp32 (64 KB contiguous), converts RNE to bf16 into one
// XOR-swizzled 32 KB LDS tile, computes both 256-row M tiles (2 subtiles of
// 64 q-rows), exp-folds into register row sums, ONE barrier total, direct
// float4 stores to gbuf[bid*512 + m].
// NOTE: plain __launch_bounds__(256) — a (256,2) min-occupancy cap forced
// ~97 MB/dispatch of scratch spills (R9: WRITE_SIZE 58.9 MB vs 1 MB legit).
// A-frags are reloaded at the top of each mt (L2-hot, 16 KB) instead of
// being held live across the exp section.
// LDS layout: element (row, k) at row*128 + (((k>>3) ^ (row&15))<<3) + (k&7).
__global__ __launch_bounds__(256) void gemm_exp_512_kernel(
        const unsigned short* __restrict__ abf,
        const float* __restrict__ Qf,
        float* __restrict__ gbuf) {
    __shared__ unsigned short Bs[128 * 128];      // 32 KB

    const int tid  = threadIdx.x;
    const int bid  = blockIdx.x;
    const int nb   = bid * 128;                   // queue row base

    const int w    = tid >> 6;
    const int lane = tid & 63;
    const int quad = lane >> 4;
    const int l16  = lane & 15;
    const int wrow = w * 64;                      // wave owns 64 M rows / mt

    // ---- stage B: 128x128 fp32 -> bf16, swizzled (16 float4/thread) ----
    #pragma unroll
    for (int i = 0; i < 16; ++i) {
        const int idx = i * 256 + tid;            // float4 index in tile
        const int row = idx >> 5;
        const int c4  = idx & 31;
        const float4 q = *reinterpret_cast<const float4*>(Qf + (nb + row) * 128 + c4 * 4);
        uint2 p;
        p.x = pk2(q.x, q.y);
        p.y = pk2(q.z, q.w);
        const int chunk = (c4 >> 1) ^ (row & 15);
        *reinterpret_cast<uint2*>(&Bs[row * 128 + (chunk << 3) + ((c4 & 1) << 2)]) = p;
    }

    // Prefetch mt=0 A-frags while Bs staging drains (independent of LDS).
    short8 a[4][4];
    #pragma unroll
    for (int mi = 0; mi < 4; ++mi)
        #pragma unroll
        for (int kk = 0; kk < 4; ++kk)
            a[mi][kk] = *(const short8*)&abf[(wrow + mi * 16 + l16) * 128
                                             + (kk * 4 + quad) * 8];
    __syncthreads();                               // the ONLY barrier

    #pragma unroll 1
    for (int mt = 0; mt < 2; ++mt) {
        if (mt == 1) {                             // reload A-frags (L2-hot)
            #pragma unroll
            for (int mi = 0; mi < 4; ++mi)
                #pragma unroll
                for (int kk = 0; kk < 4; ++kk)
                    a[mi][kk] = *(const short8*)&abf[(256 + wrow + mi * 16 + l16) * 128
                                                     + (kk * 4 + quad) * 8];
        }

        float rs[4][4];
        #pragma unroll
        for (int mi = 0; mi < 4; ++mi)
            #pragma unroll
            for (int r = 0; r < 4; ++r) rs[mi][r] = 0.0f;

        #pragma unroll
        for (int sub = 0; sub < 2; ++sub) {       // 64 queue rows each
            float4v acc[4][4];
            #pragma unroll
            for (int mi = 0; mi < 4; ++mi)
                #pragma unroll
                for (int ni = 0; ni < 4; ++ni)
                    acc[mi][ni] = (float4v){0.f, 0.f, 0.f, 0.f};

            #pragma unroll
            for (int kk = 0; kk < 4; ++kk) {
                const int c = kk * 4 + quad;
                short8 b[4];
                #pragma unroll
                for (int ni = 0; ni < 4; ++ni) {
                    const int row = sub * 64 + ni * 16 + l16;
                    b[ni] = *(const short8*)&Bs[row * 128 + ((c ^ (row & 15)) << 3)];
                }
                #pragma unroll
                for (int mi = 0; mi < 4; ++mi)
                    #pragma unroll
                    for (int ni = 0; ni < 4; ++ni)
                        acc[mi][ni] = __builtin_amdgcn_mfma_f32_16x16x32_bf16(
                            a[mi][kk], b[ni], acc[mi][ni], 0, 0, 0);
            }

            // exp(10*x) = 2^(x * 10/ln2)
            #pragma unroll
            for (int mi = 0; mi < 4; ++mi)
                #pragma unroll
                for (int ni = 0; ni < 4; ++ni)
                    #pragma unroll
                    for (int r = 0; r < 4; ++r)
                        rs[mi][r] += exp2f(acc[mi][ni][r] * 14.426950408889634f);
        }

        // reduce over 16 n-cols; lane l16==0 holds contiguous rows quad*4..+3
        #pragma unroll
        for (int mi = 0; mi < 4; ++mi) {
            #pragma unroll
            for (int r = 0; r < 4; ++r) {
                rs[mi][r] += __shfl_xor(rs[mi][r], 1);
                rs[mi][r] += __shfl_xor(rs[mi][r], 2);
                rs[mi][r] += __shfl_xor(rs[mi][r], 4);
                rs[mi][r] += __shfl_xor(rs[mi][r], 8);
            }
            if (l16 == 0)
                *reinterpret_cast<float4*>(
                    &gbuf[bid * 512 + mt * 256 + wrow + mi * 16 + quad * 4]) =
                    make_float4(rs[mi][0], rs[mi][1], rs[mi][2], rs[mi][3]);
        }
    }
}

// Backend: 32 blocks x 1024. Phase A: block b reduces gbuf slices
// [b*16, b*16+16) -> gbuf2[b*512+m] (coalesced). Then fence + ticket; the
// LAST block re-reads all 32 slices via agent-scope atomic loads, computes
// pos from L2-hot V.L, Sp, and the loss.
__global__ __launch_bounds__(1024) void backend_kernel(
        const float* __restrict__ V, const float* __restrict__ L,
        const float* __restrict__ gbuf, float* __restrict__ gbuf2,
        unsigned int* __restrict__ ticket, float* __restrict__ out) {
    __shared__ float comb[1024];
    __shared__ float comb2[1024];
    __shared__ float wsum[16];
    __shared__ unsigned int lastFlag;

    const int tid  = threadIdx.x;
    const int b    = blockIdx.x;
    const int m    = tid & 511;
    const int h    = tid >> 9;                     // 0/1
    const int w    = tid >> 6;
    const int lane = tid & 63;

    // ---- phase A: fold 16 slices -> 1 ----
    {
        float s = 0.0f;
        const int sbase = b * 16 + h * 8;
        #pragma unroll
        for (int k = 0; k < 8; ++k)
            s += gbuf[((sbase + k) << 9) + m];
        comb[tid] = s;
    }
    __syncthreads();
    if (tid < 512) gbuf2[(b << 9) + tid] = comb[tid] + comb[tid + 512];
    __threadfence();
    __syncthreads();
    if (tid == 0) lastFlag = (atomicAdd(ticket, 1u) == 31u) ? 1u : 0u;
    __syncthreads();
    if (lastFlag == 0u) return;
    __threadfence();

    // ---- last block: Sq[m] from gbuf2 (agent-scope loads) ----
    {
        float s = 0.0f;
        #pragma unroll
        for (int k = 0; k < 16; ++k)
            s += __hip_atomic_load(&gbuf2[((h * 16 + k) << 9) + m],
                                   __ATOMIC_RELAXED, __HIP_MEMORY_SCOPE_AGENT);
        comb[tid] = s;
    }
    // pos[m] = 10 * dot(V[m], L[m&255]) — split over h halves
    {
        const float4* vr = (const float4*)(V + m * 128 + h * 64);
        const float4* lr = (const float4*)(L + (m & 255) * 128 + h * 64);
        float d = 0.0f;
        #pragma unroll
        for (int i = 0; i < 16; ++i) {
            const float4 a4 = vr[i];
            const float4 b4 = lr[i];
            d += a4.x * b4.x + a4.y * b4.y + a4.z * b4.z + a4.w * b4.w;
        }
        comb2[tid] = 10.0f * d;
    }
    __syncthreads();

    float Sqm = 0.0f, posm = 0.0f;
    if (tid < 512) {
        Sqm  = comb[tid] + comb[tid + 512];
        posm = comb2[tid] + comb2[tid + 512];
    }

    // Sp[j] = sum_b exp(pos[j*256+b]); t<512 spans waves 0..7 (j = t>>8)
    float e = (tid < 512) ? __expf(posm) : 0.0f;
    #pragma unroll
    for (int off = 32; off; off >>= 1) e += __shfl_xor(e, off);
    if (lane == 0) wsum[w] = e;
    __syncthreads();
    const float Sp0 = wsum[0] + wsum[1] + wsum[2] + wsum[3];
    const float Sp1 = wsum[4] + wsum[5] + wsum[6] + wsum[7];

    float contrib = 0.0f;
    if (tid < 512) contrib = posm - __logf(((tid >> 8) ? Sp1 : Sp0) + Sqm);
    #pragma unroll
    for (int off = 32; off; off >>= 1) contrib += __shfl_xor(contrib, off);
    __syncthreads();
    if (lane == 0) wsum[w] = contrib;
    __syncthreads();
    if (tid == 0) {
        float tot = 0.0f;
        #pragma unroll
        for (int i = 0; i < 8; ++i) tot += wsum[i];
        out[0] = -tot / 256.0f;
    }
}

// ======================================================= fallback path ====

__global__ void prep_kernel(const float* __restrict__ V,
                            const float* __restrict__ L,
                            float* __restrict__ pos,
                            float* __restrict__ Sq) {
    const int blk  = blockIdx.x;
    const int tid  = threadIdx.x;
    if (tid < 8) Sq[blk * 8 + tid] = 0.0f;
    const int w    = tid >> 6;
    const int lane = tid & 63;
    #pragma unroll
    for (int i = 0; i < 2; ++i) {
        const int r = blk * 8 + w * 2 + i;
        const int b = r & 255;
        const float2 v = *reinterpret_cast<const float2*>(V + r * 128 + lane * 2);
        const float2 l = *reinterpret_cast<const float2*>(L + b * 128 + lane * 2);
        float p = v.x * l.x + v.y * l.y;
        #pragma unroll
        for (int off = 32; off; off >>= 1) p += __shfl_xor(p, off);
        if (lane == 0) pos[r] = 10.0f * p;
    }
}

__global__ __launch_bounds__(256) void gemm_exp_fallback(
        const float* __restrict__ V,
        const float* __restrict__ Q,
        float* __restrict__ Sq) {
    __shared__ unsigned short As[128 * 128];
    __shared__ unsigned short Bs[128 * 128];
    const int tid = threadIdx.x;
    const int m0  = blockIdx.y * 128;
    const int n0  = blockIdx.x * 128;
    #pragma unroll
    for (int i = 0; i < 16; ++i) {
        const int idx = i * 256 + tid;
        const int row = idx >> 5;
        const int c4  = idx & 31;
        const float4 a = *reinterpret_cast<const float4*>(V + (m0 + row) * 128 + c4 * 4);
        const float4 b = *reinterpret_cast<const float4*>(Q + (n0 + row) * 128 + c4 * 4);
        const int chunk = ((c4 >> 1) ^ (row & 15));
        const int off   = row * 128 + (chunk << 3) + ((c4 & 1) << 2);
        const uint2 pa = make_uint2(pk2(a.x, a.y), pk2(a.z, a.w));
        const uint2 pb = make_uint2(pk2(b.x, b.y), pk2(b.z, b.w));
        *reinterpret_cast<uint2*>(&As[off]) = pa;
        *reinterpret_cast<uint2*>(&Bs[off]) = pb;
    }
    __syncthreads();
    const int w    = tid >> 6;
    const int lane = tid & 63;
    const int quad = lane >> 4;
    const int l16  = lane & 15;
    const int wrow = (w >> 1) * 64;
    const int wcol = (w & 1) * 64;
    float4v acc[4][4];
    #pragma unroll
    for (int mi = 0; mi < 4; ++mi)
        #pragma unroll
        for (int ni = 0; ni < 4; ++ni)
            acc[mi][ni] = (float4v){0.f, 0.f, 0.f, 0.f};
    #pragma unroll
    for (int kk = 0; kk < 4; ++kk) {
        const int kchunk = kk * 4 + quad;
        short8 a[4], b[4];
        #pragma unroll
        for (int mi = 0; mi < 4; ++mi) {
            const int row = wrow + mi * 16 + l16;
            a[mi] = *reinterpret_cast<const short8*>(&As[row * 128 + ((kchunk ^ (row & 15)) << 3)]);
        }
        #pragma unroll
        for (int ni = 0; ni < 4; ++ni) {
            const int row = wcol + ni * 16 + l16;
            b[ni] = *reinterpret_cast<const short8*>(&Bs[row * 128 + ((kchunk ^ (row & 15)) << 3)]);
        }
        #pragma unroll
        for (int mi = 0; mi < 4; ++mi)
            #pragma unroll
            for (int ni = 0; ni < 4; ++ni)
                acc[mi][ni] = __builtin_amdgcn_mfma_f32_16x16x32_bf16(a[mi], b[ni], acc[mi][ni], 0, 0, 0);
    }
    __syncthreads();
    float* rowsum = reinterpret_cast<float*>(As);
    #pragma unroll
    for (int mi = 0; mi < 4; ++mi) {
        float rsv[4] = {0.f, 0.f, 0.f, 0.f};
        #pragma unroll
        for (int ni = 0; ni < 4; ++ni)
            #pragma unroll
            for (int r = 0; r < 4; ++r)
                rsv[r] += __expf(10.0f * acc[mi][ni][r]);
        #pragma unroll
        for (int r = 0; r < 4; ++r) {
            float vsum = rsv[r];
            vsum += __shfl_xor(vsum, 1);
            vsum += __shfl_xor(vsum, 2);
            vsum += __shfl_xor(vsum, 4);
            vsum += __shfl_xor(vsum, 8);
            if (l16 == 0)
                rowsum[(w & 1) * 128 + wrow + mi * 16 + quad * 4 + r] = vsum;
        }
    }
    __syncthreads();
    if (tid < 128)
        atomicAdd(&Sq[m0 + tid], rowsum[tid] + rowsum[128 + tid]);
}

__global__ void finalize_kernel(const float* __restrict__ pos,
                                const float* __restrict__ Sq,
                                float* __restrict__ out) {
    __shared__ float wsum[8];
    __shared__ float Sp[2];
    const int tid  = threadIdx.x;
    const int w    = tid >> 6;
    const int lane = tid & 63;
    const float p = pos[tid];
    float e = __expf(p);
    #pragma unroll
    for (int off = 32; off; off >>= 1) e += __shfl_xor(e, off);
    if (lane == 0) wsum[w] = e;
    __syncthreads();
    if (tid == 0) {
        Sp[0] = wsum[0] + wsum[1] + wsum[2] + wsum[3];
        Sp[1] = wsum[4] + wsum[5] + wsum[6] + wsum[7];
    }
    __syncthreads();
    const int j = tid >> 8;
    float contrib = p - __logf(Sp[j] + Sq[tid]);
    #pragma unroll
    for (int off = 32; off; off >>= 1) contrib += __shfl_xor(contrib, off);
    if (lane == 0) wsum[w] = contrib;
    __syncthreads();
    if (tid == 0) {
        float tot = 0.f;
        #pragma unroll
        for (int i = 0; i < 8; ++i) tot += wsum[i];
        out[0] = -tot / 256.0f;
    }
}

// ======================================================= launch ===========

extern "C" void kernel_launch(void* const* d_in, const int* in_sizes, int n_in,
                              void* d_out, int out_size, void* d_ws, size_t ws_size,
                              hipStream_t stream) {
    const float* V     = (const float*)d_in[0];   // (2,256,128)
    const float* L     = (const float*)d_in[1];   // (256,128)
    const float* queue = (const float*)d_in[2];   // (65536,128)
    float* out = (float*)d_out;

    const size_t need = (size_t)512 * 128 * 2 + (size_t)512 * 512 * 4
                      + (size_t)32 * 512 * 4 + 64;
    if (ws_size >= need) {
        unsigned short* abf = (unsigned short*)d_ws;          // 512x128 bf16
        float* gbuf  = (float*)(abf + 512 * 128);             // 512x512
        float* gbuf2 = gbuf + (size_t)512 * 512;              // 32x512
        unsigned int* tick = (unsigned int*)(gbuf2 + 32 * 512);
        prep_kernel_fast<<<64, 256, 0, stream>>>(V, abf, tick);
        gemm_exp_512_kernel<<<512, 256, 0, stream>>>(abf, queue, gbuf);
        backend_kernel<<<32, 1024, 0, stream>>>(V, L, gbuf, gbuf2, tick, out);
    } else {
        float* pos = (float*)d_ws;
        float* Sq  = pos + 512;
        prep_kernel<<<64, 256, 0, stream>>>(V, L, pos, Sq);
        dim3 grid(512, 4);
        gemm_exp_fallback<<<grid, 512, 0, stream>>>(V, queue, Sq);
        finalize_kernel<<<1, 512, 0, stream>>>(pos, Sq, out);
    }
}